// Round 1
// baseline (5431.100 us; speedup 1.0000x reference)
//
#include <hip/hip_runtime.h>

// CRF forward chain on MI355X — linearized: u' = (1/g) diag(exp(h_s)) E u,
// E = exp(transitions) packed as f16 pairs (register-resident, 128 VGPR/lane).
// answer = C + log(sum_j exp(T[END,j]) u_j).
// R7: 16 chunks (Perron-Frobenius, BURN-step burn-in) x 32 blocks x 512 threads
// (8 waves, 64 rows/block) = 512 blocks, 2 blocks/CU (launch_bounds(512,4),
// VGPR cap 128 == current usage). Critical path 1048 -> 536 dependent steps.
// DATAFLOW SYNC as R6: sign-tagged u, poll IS the load; only WAVE 0 of each
// block polls; it normalizes + packs to f16 and broadcasts via LDS (4KB);
// other waves pick up after one __syncthreads. Single barrier per step; LDS
// overwrite is race-free by the dataflow chain.
//
// ws floats: u_bufs[16][2][2048] @0, usave[16][2048] @65536,
// ufin[16][2048] @98304, cbuf[16] @131072 ; posts int[512*8] @byte 524544.

#define TSZ   2048
#define NCH   16
#define GBLK  32
#define NW    8
#define CH_LEN 512
#define BURN  24
#define START_I 0
#define END_I   1

typedef float v4f __attribute__((ext_vector_type(4)));
typedef _Float16 h2f __attribute__((ext_vector_type(2)));

__device__ __forceinline__ h2f pk16(float a, float b) {
    return __builtin_bit_cast(h2f, __builtin_amdgcn_cvt_pkrtz(a, b));
}
__device__ __forceinline__ void st_coh(float* p, float v) {
    asm volatile("global_store_dword %0, %1, off sc0 sc1"
                 :: "v"(p), "v"(v) : "memory");
}
__device__ __forceinline__ float ld_coh1(const float* p) {
    float r;
    asm volatile("global_load_dword %0, %1, off sc0 sc1\n\ts_waitcnt vmcnt(0)"
                 : "=&v"(r) : "v"(p) : "memory");
    return r;
}
__device__ __forceinline__ v4f ld_coh4(const float* p) {
    v4f r;
    asm volatile("global_load_dwordx4 %0, %1, off sc0 sc1\n\ts_waitcnt vmcnt(0)"
                 : "=&v"(r) : "v"(p) : "memory");
    return r;
}

__global__ __launch_bounds__(512, 4)
void crf_chain(const float* __restrict__ h, const float* __restrict__ tr,
               float* __restrict__ out, float* __restrict__ ws)
{
    const int tid  = threadIdx.x;
    const int lane = tid & 63;
    const int wv   = tid >> 6;          // 0..7
    const int blk  = blockIdx.x;
    const int c    = blk >> 5;          // chunk id 0..15
    const int b    = blk & (GBLK - 1);  // block within chunk 0..31
    const int row_base = b * 64 + wv * 8;

    float* u_bufs = ws;                               // [NCH][2][TSZ]
    float* usave  = ws + NCH * 2 * TSZ;               // [NCH][TSZ]
    float* ufin   = usave + NCH * TSZ;                // [NCH][TSZ]
    float* cbuf   = ufin + NCH * TSZ;                 // [NCH]
    int*   posts  = (int*)((char*)ws + 524544);       // [512*8] per-wave completion

    // ---- one-time: E fragment, f16-pair packed. Lane covers cols 4*lane + 256*k + m.
    h2f e2[8][16];
    #pragma unroll
    for (int r = 0; r < 8; ++r) {
        const float* trow = tr + (size_t)(row_base + r) * TSZ + 4 * lane;
        #pragma unroll
        for (int k = 0; k < 8; ++k) {
            float4 t4 = *(const float4*)(trow + 256 * k);
            e2[r][2 * k]     = pk16(__expf(t4.x), __expf(t4.y));
            e2[r][2 * k + 1] = pk16(__expf(t4.z), __expf(t4.w));
        }
    }

    const int s_keep  = c * CH_LEN;
    const int s_begin = (c == 0) ? 0 : (s_keep - BURN);
    const int s_end   = s_keep + CH_LEN;
    const int T_iter  = s_end - s_begin;

    const int q    = ((lane & 1) << 2) | (lane & 2) | ((lane >> 2) & 1);
    const int grow = row_base + q;

    __shared__ unsigned long long uh_sh[512];   // 2048 normalized f16 values

    // ---- init: u^0 into buf parity 0, POSITIVE tag (poison 0xAA.. is negative)
    if (tid < 64) {
        int row = b * 64 + tid;
        float v = (c == 0) ? ((row == START_I) ? 1.0f : 0.0f) : 1.0f;
        st_coh(&u_bufs[(c * 2 + 0) * TSZ + row], v);
    }

    float Chat = 0.0f;

    for (int t = 0; t < T_iter; ++t) {
        const int s = s_begin + t;
        float* u_out = u_bufs + (c * 2 + ((t + 1) & 1)) * TSZ;
        const int out_neg = ((t + 1) >> 1) & 1;    // tag we write

        // prefetch emission (plain cached load) to overlap the wait
        float hv = 0.0f;
        if (lane < 8) hv = h[(size_t)s * TSZ + grow];

        if (wv == 0) {
            const float* u_in = u_bufs + (c * 2 + (t & 1)) * TSZ;
            const int in_neg  = (t >> 1) & 1;      // expected tag of u_in

            // ---- poll-by-load: re-load until every value carries the expected sign
            v4f u0, u1, u2, u3, u4, u5, u6, u7;
            const float* pa = u_in + 4 * lane;       // k=0..3
            const float* pb = pa + 1024;             // k=4..7
            for (;;) {
                asm volatile(
                    "global_load_dwordx4 %0, %8, off sc0 sc1\n\t"
                    "global_load_dwordx4 %1, %8, off offset:1024 sc0 sc1\n\t"
                    "global_load_dwordx4 %2, %8, off offset:2048 sc0 sc1\n\t"
                    "global_load_dwordx4 %3, %8, off offset:3072 sc0 sc1\n\t"
                    "global_load_dwordx4 %4, %9, off sc0 sc1\n\t"
                    "global_load_dwordx4 %5, %9, off offset:1024 sc0 sc1\n\t"
                    "global_load_dwordx4 %6, %9, off offset:2048 sc0 sc1\n\t"
                    "global_load_dwordx4 %7, %9, off offset:3072 sc0 sc1\n\t"
                    "s_waitcnt vmcnt(0)"
                    : "=&v"(u0), "=&v"(u1), "=&v"(u2), "=&v"(u3),
                      "=&v"(u4), "=&v"(u5), "=&v"(u6), "=&v"(u7)
                    : "v"(pa), "v"(pb)
                    : "memory");
                bool fresh;
                if (in_neg) {
                    int a = __float_as_int(u0.x) & __float_as_int(u0.y) & __float_as_int(u0.z) & __float_as_int(u0.w);
                    a &= __float_as_int(u1.x) & __float_as_int(u1.y) & __float_as_int(u1.z) & __float_as_int(u1.w);
                    a &= __float_as_int(u2.x) & __float_as_int(u2.y) & __float_as_int(u2.z) & __float_as_int(u2.w);
                    a &= __float_as_int(u3.x) & __float_as_int(u3.y) & __float_as_int(u3.z) & __float_as_int(u3.w);
                    a &= __float_as_int(u4.x) & __float_as_int(u4.y) & __float_as_int(u4.z) & __float_as_int(u4.w);
                    a &= __float_as_int(u5.x) & __float_as_int(u5.y) & __float_as_int(u5.z) & __float_as_int(u5.w);
                    a &= __float_as_int(u6.x) & __float_as_int(u6.y) & __float_as_int(u6.z) & __float_as_int(u6.w);
                    a &= __float_as_int(u7.x) & __float_as_int(u7.y) & __float_as_int(u7.z) & __float_as_int(u7.w);
                    fresh = (a < 0);                   // all sign bits set
                } else {
                    int o = __float_as_int(u0.x) | __float_as_int(u0.y) | __float_as_int(u0.z) | __float_as_int(u0.w);
                    o |= __float_as_int(u1.x) | __float_as_int(u1.y) | __float_as_int(u1.z) | __float_as_int(u1.w);
                    o |= __float_as_int(u2.x) | __float_as_int(u2.y) | __float_as_int(u2.z) | __float_as_int(u2.w);
                    o |= __float_as_int(u3.x) | __float_as_int(u3.y) | __float_as_int(u3.z) | __float_as_int(u3.w);
                    o |= __float_as_int(u4.x) | __float_as_int(u4.y) | __float_as_int(u4.z) | __float_as_int(u4.w);
                    o |= __float_as_int(u5.x) | __float_as_int(u5.y) | __float_as_int(u5.z) | __float_as_int(u5.w);
                    o |= __float_as_int(u6.x) | __float_as_int(u6.y) | __float_as_int(u6.z) | __float_as_int(u6.w);
                    o |= __float_as_int(u7.x) | __float_as_int(u7.y) | __float_as_int(u7.z) | __float_as_int(u7.w);
                    fresh = (o >= 0);                  // all sign bits clear
                }
                if (__all(fresh)) break;
            }

            // ---- gmax = max |u_in| (bitwise-identical in every polling wave)
            float m;
            m =          fmaxf(fmaxf(fabsf(u0.x), fabsf(u0.y)), fmaxf(fabsf(u0.z), fabsf(u0.w)));
            m = fmaxf(m, fmaxf(fmaxf(fabsf(u1.x), fabsf(u1.y)), fmaxf(fabsf(u1.z), fabsf(u1.w))));
            m = fmaxf(m, fmaxf(fmaxf(fabsf(u2.x), fabsf(u2.y)), fmaxf(fabsf(u2.z), fabsf(u2.w))));
            m = fmaxf(m, fmaxf(fmaxf(fabsf(u3.x), fabsf(u3.y)), fmaxf(fabsf(u3.z), fabsf(u3.w))));
            m = fmaxf(m, fmaxf(fmaxf(fabsf(u4.x), fabsf(u4.y)), fmaxf(fabsf(u4.z), fabsf(u4.w))));
            m = fmaxf(m, fmaxf(fmaxf(fabsf(u5.x), fabsf(u5.y)), fmaxf(fabsf(u5.z), fabsf(u5.w))));
            m = fmaxf(m, fmaxf(fmaxf(fabsf(u6.x), fabsf(u6.y)), fmaxf(fabsf(u6.z), fabsf(u6.w))));
            m = fmaxf(m, fmaxf(fmaxf(fabsf(u7.x), fabsf(u7.y)), fmaxf(fabsf(u7.z), fabsf(u7.w))));
            #pragma unroll
            for (int d = 1; d < 64; d <<= 1) m = fmaxf(m, __shfl_xor(m, d, 64));

            // normalize (fold input sign), pack to f16, broadcast via LDS
            const float rn = (in_neg ? -1.0f : 1.0f) / m;
            h2f uh[16];
            uh[0]  = pk16(u0.x * rn, u0.y * rn);  uh[1]  = pk16(u0.z * rn, u0.w * rn);
            uh[2]  = pk16(u1.x * rn, u1.y * rn);  uh[3]  = pk16(u1.z * rn, u1.w * rn);
            uh[4]  = pk16(u2.x * rn, u2.y * rn);  uh[5]  = pk16(u2.z * rn, u2.w * rn);
            uh[6]  = pk16(u3.x * rn, u3.y * rn);  uh[7]  = pk16(u3.z * rn, u3.w * rn);
            uh[8]  = pk16(u4.x * rn, u4.y * rn);  uh[9]  = pk16(u4.z * rn, u4.w * rn);
            uh[10] = pk16(u5.x * rn, u5.y * rn);  uh[11] = pk16(u5.z * rn, u5.w * rn);
            uh[12] = pk16(u6.x * rn, u6.y * rn);  uh[13] = pk16(u6.z * rn, u6.w * rn);
            uh[14] = pk16(u7.x * rn, u7.y * rn);  uh[15] = pk16(u7.z * rn, u7.w * rn);
            #pragma unroll
            for (int k = 0; k < 8; ++k) {
                unsigned long long qw =
                    ((unsigned long long)__builtin_bit_cast(unsigned, uh[2 * k + 1]) << 32) |
                    (unsigned long long)__builtin_bit_cast(unsigned, uh[2 * k]);
                uh_sh[lane + 64 * k] = qw;
            }

            // log-scale accumulation for kept steps (m==1.0 at t==0 -> adds 0)
            if ((s + 1) > s_keep) Chat += __logf(m);
        }

        __syncthreads();   // LDS(t) ready; overwrite at t+1 is dataflow-safe

        // ---- all waves: unpack normalized u from LDS
        h2f uh[16];
        #pragma unroll
        for (int k = 0; k < 8; ++k) {
            unsigned long long qw = uh_sh[lane + 64 * k];
            uh[2 * k]     = __builtin_bit_cast(h2f, (unsigned)qw);
            uh[2 * k + 1] = __builtin_bit_cast(h2f, (unsigned)(qw >> 32));
        }

        // ---- GEMV via v_dot2_f32_f16: acc[r] = sum_j E[row_base+r][j] * u_norm[j]
        float acc[8];
        #pragma unroll
        for (int r = 0; r < 8; ++r) acc[r] = 0.0f;
        #pragma unroll
        for (int k = 0; k < 16; ++k) {
            #pragma unroll
            for (int r = 0; r < 8; ++r)
                acc[r] = __builtin_amdgcn_fdot2(e2[r][k], uh[k], acc[r], false);
        }

        // ---- multi-row butterfly: 8 rows x 64 lanes -> row q(lane), lanes 0..7
        #pragma unroll
        for (int r = 0; r < 4; ++r) {
            float send = (lane & 1) ? acc[r] : acc[r + 4];
            float recv = __shfl_xor(send, 1, 64);
            float keep = (lane & 1) ? acc[r + 4] : acc[r];
            acc[r] = keep + recv;
        }
        #pragma unroll
        for (int r = 0; r < 2; ++r) {
            float send = (lane & 2) ? acc[r] : acc[r + 2];
            float recv = __shfl_xor(send, 2, 64);
            float keep = (lane & 2) ? acc[r + 2] : acc[r];
            acc[r] = keep + recv;
        }
        {
            float send = (lane & 4) ? acc[0] : acc[1];
            float recv = __shfl_xor(send, 4, 64);
            float keep = (lane & 4) ? acc[1] : acc[0];
            acc[0] = keep + recv;
        }
        acc[0] += __shfl_xor(acc[0], 8, 64);
        acc[0] += __shfl_xor(acc[0], 16, 64);
        acc[0] += __shfl_xor(acc[0], 32, 64);

        if (lane < 8) {
            float ut = acc[0] * __expf(hv);        // true (positive) value
            st_coh(&u_out[grow], out_neg ? -ut : ut);
            if (c > 0 && (s + 1) == s_keep) st_coh(&usave[c * TSZ + grow], ut);
            if ((s + 1) == s_end)           st_coh(&ufin[c * TSZ + grow], ut);
        }
    }

    // ---- completion: ack all my stores at L3, then per-wave post
    if (b == 0 && wv == 0 && lane == 0) st_coh(&cbuf[c], Chat);
    asm volatile("s_waitcnt vmcnt(0)" ::: "memory");
    if (lane == 0)
        __hip_atomic_store(&posts[blk * NW + wv], 1,
                           __ATOMIC_RELAXED, __HIP_MEMORY_SCOPE_AGENT);

    // ---- finisher: chunk 0 / block 0 / wave 0 stitches chunks, writes scalar
    if (c == 0 && b == 0 && wv == 0) {
        int ok;
        do {
            __builtin_amdgcn_s_sleep(1);
            ok = 1;
            #pragma unroll
            for (int i = 0; i < 64; ++i) {
                int v = __hip_atomic_load(&posts[lane + 64 * i],
                                          __ATOMIC_RELAXED, __HIP_MEMORY_SCOPE_AGENT);
                ok &= (v == 1);
            }
        } while (!__all(ok));

        // stitch: match log(sum u) at chunk boundaries
        float O = 0.0f;
        for (int cc = 1; cc < NCH; ++cc) {
            float sa = 0.0f, sb = 0.0f;
            for (int j = 4 * lane; j < TSZ; j += 256) {
                v4f a4 = ld_coh4(&ufin[(cc - 1) * TSZ + j]);
                v4f b4 = ld_coh4(&usave[cc * TSZ + j]);
                sa += a4.x + a4.y + a4.z + a4.w;
                sb += b4.x + b4.y + b4.z + b4.w;
            }
            #pragma unroll
            for (int d = 1; d < 64; d <<= 1) {
                sa += __shfl_xor(sa, d, 64);
                sb += __shfl_xor(sb, d, 64);
            }
            O += ld_coh1(&cbuf[cc - 1]) + __logf(sa) - __logf(sb);
        }
        // terminal: O + C_last + log(sum_j exp(T[END,j]) u_j)
        float se = 0.0f;
        for (int j = 4 * lane; j < TSZ; j += 256) {
            const float4 t4 = *(const float4*)(tr + (size_t)END_I * TSZ + j);
            v4f uf = ld_coh4(&ufin[(NCH - 1) * TSZ + j]);
            se += __expf(t4.x) * uf.x + __expf(t4.y) * uf.y +
                  __expf(t4.z) * uf.z + __expf(t4.w) * uf.w;
        }
        #pragma unroll
        for (int d = 1; d < 64; d <<= 1) se += __shfl_xor(se, d, 64);

        float ans = O + ld_coh1(&cbuf[NCH - 1]) + __logf(se);
        if (lane == 0) out[0] = ans;
    }
}

extern "C" void kernel_launch(void* const* d_in, const int* in_sizes, int n_in,
                              void* d_out, int out_size, void* d_ws, size_t ws_size,
                              hipStream_t stream) {
    const float* h  = (const float*)d_in[0];   // [8192, 2048] fp32 emissions
    const float* tr = (const float*)d_in[1];   // [2048, 2048] fp32 transitions
    (void)in_sizes; (void)n_in; (void)out_size; (void)ws_size;
    crf_chain<<<dim3(NCH * GBLK), dim3(512), 0, stream>>>(h, tr, (float*)d_out, (float*)d_ws);
}

// Round 2
// 4069.345 us; speedup vs baseline: 1.3346x; 1.3346x over previous
//
#include <hip/hip_runtime.h>

// CRF forward chain on MI355X — linearized: u' = (1/g) diag(exp(h_s)) E u,
// E = exp(transitions) packed as f16 pairs (register-resident, 128 VGPR/lane).
// answer = C + log(sum_j exp(T[END,j]) u_j).
// R8: 16 chunks (Perron-Frobenius, BURN-step burn-in) x 32 blocks x 512 threads
// (8 waves, 64 rows/block) = 512 blocks, targeting 2 blocks/CU.
// launch_bounds(512,2): R7's (512,4) capped VGPRs at 64 -> e2[] spilled to
// scratch (FETCH 318MB->4.9GB, 2x regression). At (512,2) the compiler lands
// on 128 VGPR, which ALREADY permits 4 waves/SIMD = 2 blocks/CU; the HW
// co-schedules them since the grid has 512 blocks. Worst case (1 blk/CU) the
// chunks just run in two batches — chains are independent, no deadlock.
// DATAFLOW SYNC as R6: sign-tagged u, poll IS the load; only WAVE 0 of each
// block polls; it normalizes + packs to f16 and broadcasts via LDS (4KB);
// other waves pick up after one __syncthreads. Single barrier per step; LDS
// overwrite is race-free by the dataflow chain.
//
// ws floats: u_bufs[16][2][2048] @0, usave[16][2048] @65536,
// ufin[16][2048] @98304, cbuf[16] @131072 ; posts int[512*8] @byte 524544.

#define TSZ   2048
#define NCH   16
#define GBLK  32
#define NW    8
#define CH_LEN 512
#define BURN  24
#define START_I 0
#define END_I   1

typedef float v4f __attribute__((ext_vector_type(4)));
typedef _Float16 h2f __attribute__((ext_vector_type(2)));

__device__ __forceinline__ h2f pk16(float a, float b) {
    return __builtin_bit_cast(h2f, __builtin_amdgcn_cvt_pkrtz(a, b));
}
__device__ __forceinline__ void st_coh(float* p, float v) {
    asm volatile("global_store_dword %0, %1, off sc0 sc1"
                 :: "v"(p), "v"(v) : "memory");
}
__device__ __forceinline__ float ld_coh1(const float* p) {
    float r;
    asm volatile("global_load_dword %0, %1, off sc0 sc1\n\ts_waitcnt vmcnt(0)"
                 : "=&v"(r) : "v"(p) : "memory");
    return r;
}
__device__ __forceinline__ v4f ld_coh4(const float* p) {
    v4f r;
    asm volatile("global_load_dwordx4 %0, %1, off sc0 sc1\n\ts_waitcnt vmcnt(0)"
                 : "=&v"(r) : "v"(p) : "memory");
    return r;
}

__global__ __launch_bounds__(512, 2)
void crf_chain(const float* __restrict__ h, const float* __restrict__ tr,
               float* __restrict__ out, float* __restrict__ ws)
{
    const int tid  = threadIdx.x;
    const int lane = tid & 63;
    const int wv   = tid >> 6;          // 0..7
    const int blk  = blockIdx.x;
    const int c    = blk >> 5;          // chunk id 0..15
    const int b    = blk & (GBLK - 1);  // block within chunk 0..31
    const int row_base = b * 64 + wv * 8;

    float* u_bufs = ws;                               // [NCH][2][TSZ]
    float* usave  = ws + NCH * 2 * TSZ;               // [NCH][TSZ]
    float* ufin   = usave + NCH * TSZ;                // [NCH][TSZ]
    float* cbuf   = ufin + NCH * TSZ;                 // [NCH]
    int*   posts  = (int*)((char*)ws + 524544);       // [512*8] per-wave completion

    // ---- one-time: E fragment, f16-pair packed. Lane covers cols 4*lane + 256*k + m.
    h2f e2[8][16];
    #pragma unroll
    for (int r = 0; r < 8; ++r) {
        const float* trow = tr + (size_t)(row_base + r) * TSZ + 4 * lane;
        #pragma unroll
        for (int k = 0; k < 8; ++k) {
            float4 t4 = *(const float4*)(trow + 256 * k);
            e2[r][2 * k]     = pk16(__expf(t4.x), __expf(t4.y));
            e2[r][2 * k + 1] = pk16(__expf(t4.z), __expf(t4.w));
        }
    }

    const int s_keep  = c * CH_LEN;
    const int s_begin = (c == 0) ? 0 : (s_keep - BURN);
    const int s_end   = s_keep + CH_LEN;
    const int T_iter  = s_end - s_begin;

    const int q    = ((lane & 1) << 2) | (lane & 2) | ((lane >> 2) & 1);
    const int grow = row_base + q;

    __shared__ unsigned long long uh_sh[512];   // 2048 normalized f16 values

    // ---- init: u^0 into buf parity 0, POSITIVE tag (poison 0xAA.. is negative)
    if (tid < 64) {
        int row = b * 64 + tid;
        float v = (c == 0) ? ((row == START_I) ? 1.0f : 0.0f) : 1.0f;
        st_coh(&u_bufs[(c * 2 + 0) * TSZ + row], v);
    }

    float Chat = 0.0f;

    for (int t = 0; t < T_iter; ++t) {
        const int s = s_begin + t;
        float* u_out = u_bufs + (c * 2 + ((t + 1) & 1)) * TSZ;
        const int out_neg = ((t + 1) >> 1) & 1;    // tag we write

        // prefetch emission (plain cached load) to overlap the wait
        float hv = 0.0f;
        if (lane < 8) hv = h[(size_t)s * TSZ + grow];

        if (wv == 0) {
            const float* u_in = u_bufs + (c * 2 + (t & 1)) * TSZ;
            const int in_neg  = (t >> 1) & 1;      // expected tag of u_in

            // ---- poll-by-load: re-load until every value carries the expected sign
            v4f u0, u1, u2, u3, u4, u5, u6, u7;
            const float* pa = u_in + 4 * lane;       // k=0..3
            const float* pb = pa + 1024;             // k=4..7
            for (;;) {
                asm volatile(
                    "global_load_dwordx4 %0, %8, off sc0 sc1\n\t"
                    "global_load_dwordx4 %1, %8, off offset:1024 sc0 sc1\n\t"
                    "global_load_dwordx4 %2, %8, off offset:2048 sc0 sc1\n\t"
                    "global_load_dwordx4 %3, %8, off offset:3072 sc0 sc1\n\t"
                    "global_load_dwordx4 %4, %9, off sc0 sc1\n\t"
                    "global_load_dwordx4 %5, %9, off offset:1024 sc0 sc1\n\t"
                    "global_load_dwordx4 %6, %9, off offset:2048 sc0 sc1\n\t"
                    "global_load_dwordx4 %7, %9, off offset:3072 sc0 sc1\n\t"
                    "s_waitcnt vmcnt(0)"
                    : "=&v"(u0), "=&v"(u1), "=&v"(u2), "=&v"(u3),
                      "=&v"(u4), "=&v"(u5), "=&v"(u6), "=&v"(u7)
                    : "v"(pa), "v"(pb)
                    : "memory");
                bool fresh;
                if (in_neg) {
                    int a = __float_as_int(u0.x) & __float_as_int(u0.y) & __float_as_int(u0.z) & __float_as_int(u0.w);
                    a &= __float_as_int(u1.x) & __float_as_int(u1.y) & __float_as_int(u1.z) & __float_as_int(u1.w);
                    a &= __float_as_int(u2.x) & __float_as_int(u2.y) & __float_as_int(u2.z) & __float_as_int(u2.w);
                    a &= __float_as_int(u3.x) & __float_as_int(u3.y) & __float_as_int(u3.z) & __float_as_int(u3.w);
                    a &= __float_as_int(u4.x) & __float_as_int(u4.y) & __float_as_int(u4.z) & __float_as_int(u4.w);
                    a &= __float_as_int(u5.x) & __float_as_int(u5.y) & __float_as_int(u5.z) & __float_as_int(u5.w);
                    a &= __float_as_int(u6.x) & __float_as_int(u6.y) & __float_as_int(u6.z) & __float_as_int(u6.w);
                    a &= __float_as_int(u7.x) & __float_as_int(u7.y) & __float_as_int(u7.z) & __float_as_int(u7.w);
                    fresh = (a < 0);                   // all sign bits set
                } else {
                    int o = __float_as_int(u0.x) | __float_as_int(u0.y) | __float_as_int(u0.z) | __float_as_int(u0.w);
                    o |= __float_as_int(u1.x) | __float_as_int(u1.y) | __float_as_int(u1.z) | __float_as_int(u1.w);
                    o |= __float_as_int(u2.x) | __float_as_int(u2.y) | __float_as_int(u2.z) | __float_as_int(u2.w);
                    o |= __float_as_int(u3.x) | __float_as_int(u3.y) | __float_as_int(u3.z) | __float_as_int(u3.w);
                    o |= __float_as_int(u4.x) | __float_as_int(u4.y) | __float_as_int(u4.z) | __float_as_int(u4.w);
                    o |= __float_as_int(u5.x) | __float_as_int(u5.y) | __float_as_int(u5.z) | __float_as_int(u5.w);
                    o |= __float_as_int(u6.x) | __float_as_int(u6.y) | __float_as_int(u6.z) | __float_as_int(u6.w);
                    o |= __float_as_int(u7.x) | __float_as_int(u7.y) | __float_as_int(u7.z) | __float_as_int(u7.w);
                    fresh = (o >= 0);                  // all sign bits clear
                }
                if (__all(fresh)) break;
            }

            // ---- gmax = max |u_in| (bitwise-identical in every polling wave)
            float m;
            m =          fmaxf(fmaxf(fabsf(u0.x), fabsf(u0.y)), fmaxf(fabsf(u0.z), fabsf(u0.w)));
            m = fmaxf(m, fmaxf(fmaxf(fabsf(u1.x), fabsf(u1.y)), fmaxf(fabsf(u1.z), fabsf(u1.w))));
            m = fmaxf(m, fmaxf(fmaxf(fabsf(u2.x), fabsf(u2.y)), fmaxf(fabsf(u2.z), fabsf(u2.w))));
            m = fmaxf(m, fmaxf(fmaxf(fabsf(u3.x), fabsf(u3.y)), fmaxf(fabsf(u3.z), fabsf(u3.w))));
            m = fmaxf(m, fmaxf(fmaxf(fabsf(u4.x), fabsf(u4.y)), fmaxf(fabsf(u4.z), fabsf(u4.w))));
            m = fmaxf(m, fmaxf(fmaxf(fabsf(u5.x), fabsf(u5.y)), fmaxf(fabsf(u5.z), fabsf(u5.w))));
            m = fmaxf(m, fmaxf(fmaxf(fabsf(u6.x), fabsf(u6.y)), fmaxf(fabsf(u6.z), fabsf(u6.w))));
            m = fmaxf(m, fmaxf(fmaxf(fabsf(u7.x), fabsf(u7.y)), fmaxf(fabsf(u7.z), fabsf(u7.w))));
            #pragma unroll
            for (int d = 1; d < 64; d <<= 1) m = fmaxf(m, __shfl_xor(m, d, 64));

            // normalize (fold input sign), pack to f16, broadcast via LDS
            const float rn = (in_neg ? -1.0f : 1.0f) / m;
            h2f uh[16];
            uh[0]  = pk16(u0.x * rn, u0.y * rn);  uh[1]  = pk16(u0.z * rn, u0.w * rn);
            uh[2]  = pk16(u1.x * rn, u1.y * rn);  uh[3]  = pk16(u1.z * rn, u1.w * rn);
            uh[4]  = pk16(u2.x * rn, u2.y * rn);  uh[5]  = pk16(u2.z * rn, u2.w * rn);
            uh[6]  = pk16(u3.x * rn, u3.y * rn);  uh[7]  = pk16(u3.z * rn, u3.w * rn);
            uh[8]  = pk16(u4.x * rn, u4.y * rn);  uh[9]  = pk16(u4.z * rn, u4.w * rn);
            uh[10] = pk16(u5.x * rn, u5.y * rn);  uh[11] = pk16(u5.z * rn, u5.w * rn);
            uh[12] = pk16(u6.x * rn, u6.y * rn);  uh[13] = pk16(u6.z * rn, u6.w * rn);
            uh[14] = pk16(u7.x * rn, u7.y * rn);  uh[15] = pk16(u7.z * rn, u7.w * rn);
            #pragma unroll
            for (int k = 0; k < 8; ++k) {
                unsigned long long qw =
                    ((unsigned long long)__builtin_bit_cast(unsigned, uh[2 * k + 1]) << 32) |
                    (unsigned long long)__builtin_bit_cast(unsigned, uh[2 * k]);
                uh_sh[lane + 64 * k] = qw;
            }

            // log-scale accumulation for kept steps (m==1.0 at t==0 -> adds 0)
            if ((s + 1) > s_keep) Chat += __logf(m);
        }

        __syncthreads();   // LDS(t) ready; overwrite at t+1 is dataflow-safe

        // ---- all waves: unpack normalized u from LDS
        h2f uh[16];
        #pragma unroll
        for (int k = 0; k < 8; ++k) {
            unsigned long long qw = uh_sh[lane + 64 * k];
            uh[2 * k]     = __builtin_bit_cast(h2f, (unsigned)qw);
            uh[2 * k + 1] = __builtin_bit_cast(h2f, (unsigned)(qw >> 32));
        }

        // ---- GEMV via v_dot2_f32_f16: acc[r] = sum_j E[row_base+r][j] * u_norm[j]
        float acc[8];
        #pragma unroll
        for (int r = 0; r < 8; ++r) acc[r] = 0.0f;
        #pragma unroll
        for (int k = 0; k < 16; ++k) {
            #pragma unroll
            for (int r = 0; r < 8; ++r)
                acc[r] = __builtin_amdgcn_fdot2(e2[r][k], uh[k], acc[r], false);
        }

        // ---- multi-row butterfly: 8 rows x 64 lanes -> row q(lane), lanes 0..7
        #pragma unroll
        for (int r = 0; r < 4; ++r) {
            float send = (lane & 1) ? acc[r] : acc[r + 4];
            float recv = __shfl_xor(send, 1, 64);
            float keep = (lane & 1) ? acc[r + 4] : acc[r];
            acc[r] = keep + recv;
        }
        #pragma unroll
        for (int r = 0; r < 2; ++r) {
            float send = (lane & 2) ? acc[r] : acc[r + 2];
            float recv = __shfl_xor(send, 2, 64);
            float keep = (lane & 2) ? acc[r + 2] : acc[r];
            acc[r] = keep + recv;
        }
        {
            float send = (lane & 4) ? acc[0] : acc[1];
            float recv = __shfl_xor(send, 4, 64);
            float keep = (lane & 4) ? acc[1] : acc[0];
            acc[0] = keep + recv;
        }
        acc[0] += __shfl_xor(acc[0], 8, 64);
        acc[0] += __shfl_xor(acc[0], 16, 64);
        acc[0] += __shfl_xor(acc[0], 32, 64);

        if (lane < 8) {
            float ut = acc[0] * __expf(hv);        // true (positive) value
            st_coh(&u_out[grow], out_neg ? -ut : ut);
            if (c > 0 && (s + 1) == s_keep) st_coh(&usave[c * TSZ + grow], ut);
            if ((s + 1) == s_end)           st_coh(&ufin[c * TSZ + grow], ut);
        }
    }

    // ---- completion: ack all my stores at L3, then per-wave post
    if (b == 0 && wv == 0 && lane == 0) st_coh(&cbuf[c], Chat);
    asm volatile("s_waitcnt vmcnt(0)" ::: "memory");
    if (lane == 0)
        __hip_atomic_store(&posts[blk * NW + wv], 1,
                           __ATOMIC_RELAXED, __HIP_MEMORY_SCOPE_AGENT);

    // ---- finisher: chunk 0 / block 0 / wave 0 stitches chunks, writes scalar
    if (c == 0 && b == 0 && wv == 0) {
        int ok;
        do {
            __builtin_amdgcn_s_sleep(1);
            ok = 1;
            #pragma unroll
            for (int i = 0; i < 64; ++i) {
                int v = __hip_atomic_load(&posts[lane + 64 * i],
                                          __ATOMIC_RELAXED, __HIP_MEMORY_SCOPE_AGENT);
                ok &= (v == 1);
            }
        } while (!__all(ok));

        // stitch: match log(sum u) at chunk boundaries
        float O = 0.0f;
        for (int cc = 1; cc < NCH; ++cc) {
            float sa = 0.0f, sb = 0.0f;
            for (int j = 4 * lane; j < TSZ; j += 256) {
                v4f a4 = ld_coh4(&ufin[(cc - 1) * TSZ + j]);
                v4f b4 = ld_coh4(&usave[cc * TSZ + j]);
                sa += a4.x + a4.y + a4.z + a4.w;
                sb += b4.x + b4.y + b4.z + b4.w;
            }
            #pragma unroll
            for (int d = 1; d < 64; d <<= 1) {
                sa += __shfl_xor(sa, d, 64);
                sb += __shfl_xor(sb, d, 64);
            }
            O += ld_coh1(&cbuf[cc - 1]) + __logf(sa) - __logf(sb);
        }
        // terminal: O + C_last + log(sum_j exp(T[END,j]) u_j)
        float se = 0.0f;
        for (int j = 4 * lane; j < TSZ; j += 256) {
            const float4 t4 = *(const float4*)(tr + (size_t)END_I * TSZ + j);
            v4f uf = ld_coh4(&ufin[(NCH - 1) * TSZ + j]);
            se += __expf(t4.x) * uf.x + __expf(t4.y) * uf.y +
                  __expf(t4.z) * uf.z + __expf(t4.w) * uf.w;
        }
        #pragma unroll
        for (int d = 1; d < 64; d <<= 1) se += __shfl_xor(se, d, 64);

        float ans = O + ld_coh1(&cbuf[NCH - 1]) + __logf(se);
        if (lane == 0) out[0] = ans;
    }
}

extern "C" void kernel_launch(void* const* d_in, const int* in_sizes, int n_in,
                              void* d_out, int out_size, void* d_ws, size_t ws_size,
                              hipStream_t stream) {
    const float* h  = (const float*)d_in[0];   // [8192, 2048] fp32 emissions
    const float* tr = (const float*)d_in[1];   // [2048, 2048] fp32 transitions
    (void)in_sizes; (void)n_in; (void)out_size; (void)ws_size;
    crf_chain<<<dim3(NCH * GBLK), dim3(512), 0, stream>>>(h, tr, (float*)d_out, (float*)d_ws);
}